// Round 6
// baseline (299.918 us; speedup 1.0000x reference)
//
#include <hip/hip_runtime.h>
#include <hip/hip_bf16.h>
#include <stdint.h>

#define Nn 8192
#define Dd 256
#define TWO_N 16384
#define INV_TAU 2.0f

typedef unsigned short u16;
typedef __bf16 bf16x8 __attribute__((ext_vector_type(8)));
typedef float f32x4 __attribute__((ext_vector_type(4)));

typedef const __attribute__((address_space(1))) void* gas_ptr;
typedef __attribute__((address_space(3))) void* las_ptr;

__device__ __forceinline__ void async_copy16(const void* g, void* l) {
  __builtin_amdgcn_global_load_lds((gas_ptr)g, (las_ptr)l, 16, 0, 0);
}

__device__ __forceinline__ u16 f2bf(float x) {
  uint32_t u = __float_as_uint(x);
  u = u + 0x7fffu + ((u >> 16) & 1u);
  return (u16)(u >> 16);
}
__device__ __forceinline__ float bf2f(u16 u) {
  return __uint_as_float(((uint32_t)u) << 16);
}

// ---------------- fused cast fp32 -> bf16 ------------------------------------
__global__ void cast_all(const float* __restrict__ z1, const float* __restrict__ z2,
                         const float* __restrict__ W1, const float* __restrict__ W2,
                         u16* __restrict__ Zb, u16* __restrict__ W1b, u16* __restrict__ W2b) {
  int i = blockIdx.x * 256 + threadIdx.x;
  const float4* src; ushort4* dst; int off;
  if (i < 524288)       { src = (const float4*)z1; dst = (ushort4*)Zb;                      off = i; }
  else if (i < 1048576) { src = (const float4*)z2; dst = (ushort4*)(Zb + (size_t)Nn * Dd);  off = i - 524288; }
  else if (i < 1064960) { src = (const float4*)W1; dst = (ushort4*)W1b;                     off = i - 1048576; }
  else                  { src = (const float4*)W2; dst = (ushort4*)W2b;                     off = i - 1064960; }
  float4 v = src[off];
  ushort4 o;
  o.x = f2bf(v.x); o.y = f2bf(v.y); o.z = f2bf(v.z); o.w = f2bf(v.w);
  dst[off] = o;
}

// ---------------- layer-1 GEMM: elu(Z @ W1^T + b1) -> bf16 -------------------
__global__ __launch_bounds__(256)
void mfma_gemm1(const u16* __restrict__ A, const u16* __restrict__ B,
                const float* __restrict__ bias, u16* __restrict__ outp) {
  __shared__ __bf16 sA[128 * 64];
  __shared__ __bf16 sB[128 * 64];
  const int i0 = blockIdx.x * 128;
  const int j0 = blockIdx.y * 128;
  const int t = threadIdx.x;
  const int lane = t & 63, wave = t >> 6;
  const int wm = (wave >> 1) * 64, wn = (wave & 1) * 64;
  const int fr = lane >> 4, fc = lane & 15;
  const int sw = fc & 7;

  f32x4 acc[4][4];
#pragma unroll
  for (int a = 0; a < 4; a++)
#pragma unroll
    for (int b = 0; b < 4; b++) acc[a][b] = (f32x4){0.f, 0.f, 0.f, 0.f};

  const u16* Ag = A + (size_t)i0 * 256;
  const u16* Bg = B + (size_t)j0 * 256;

  for (int k0 = 0; k0 < 256; k0 += 64) {
    __syncthreads();
#pragma unroll
    for (int it = 0; it < 4; ++it) {
      int c = t + 256 * it;
      int row = c >> 3;
      int kc = ((c & 7) ^ (row & 7)) * 8;
      async_copy16(Ag + (size_t)row * 256 + k0 + kc, (void*)&sA[c * 8]);
      async_copy16(Bg + (size_t)row * 256 + k0 + kc, (void*)&sB[c * 8]);
    }
    __syncthreads();
#pragma unroll
    for (int ks = 0; ks < 2; ++ks) {
      bf16x8 af[4], bfr[4];
#pragma unroll
      for (int mi = 0; mi < 4; mi++)
        af[mi] = *(const bf16x8*)&sA[(wm + mi * 16 + fc) * 64 + (((ks * 4 + fr) ^ sw) * 8)];
#pragma unroll
      for (int ni = 0; ni < 4; ni++)
        bfr[ni] = *(const bf16x8*)&sB[(wn + ni * 16 + fc) * 64 + (((ks * 4 + fr) ^ sw) * 8)];
#pragma unroll
      for (int mi = 0; mi < 4; mi++)
#pragma unroll
        for (int ni = 0; ni < 4; ni++)
          acc[mi][ni] = __builtin_amdgcn_mfma_f32_16x16x32_bf16(af[mi], bfr[ni], acc[mi][ni], 0, 0, 0);
    }
  }

#pragma unroll
  for (int mi = 0; mi < 4; mi++) {
#pragma unroll
    for (int ni = 0; ni < 4; ni++) {
      int col = j0 + wn + ni * 16 + fc;
      float bv = bias[col];
#pragma unroll
      for (int r = 0; r < 4; r++) {
        int row = i0 + wm + mi * 16 + fr * 4 + r;
        float v = acc[mi][ni][r] + bv;
        v = v > 0.f ? v : (__expf(v) - 1.f);
        outp[(size_t)row * 256 + col] = f2bf(v);
      }
    }
  }
}

// ---------------- fused layer-2 GEMM + row-normalize -------------------------
// 128 blocks; each computes 128 rows x all 256 cols of H = H1 @ W2^T + b2,
// then normalizes rows in-register (cross-wave LDS reduce), writes bf16 Mb and
// snorm (from bf16-rounded values). Also zeroes rsum.
__global__ __launch_bounds__(256)
void gemm2_norm(const u16* __restrict__ A, const u16* __restrict__ B,
                const float* __restrict__ bias, u16* __restrict__ Mb,
                float* __restrict__ snorm, float* __restrict__ rsum) {
  __shared__ __bf16 sA[128 * 64];   // 16 KB
  __shared__ __bf16 sB[256 * 64];   // 32 KB
  const int i0 = blockIdx.x * 128;
  const int t = threadIdx.x;
  const int lane = t & 63, wave = t >> 6;
  const int wm = (wave >> 1) * 64, wn = (wave & 1) * 128;
  const int fr = lane >> 4, fc = lane & 15;
  const int sw = fc & 7;

  if (t < 128) rsum[i0 + t] = 0.f;

  f32x4 acc[4][8];
#pragma unroll
  for (int a = 0; a < 4; a++)
#pragma unroll
    for (int b = 0; b < 8; b++) acc[a][b] = (f32x4){0.f, 0.f, 0.f, 0.f};

  const u16* Ag = A + (size_t)i0 * 256;

  for (int k0 = 0; k0 < 256; k0 += 64) {
    __syncthreads();
#pragma unroll
    for (int it = 0; it < 4; ++it) {
      int c = t + 256 * it;
      int row = c >> 3;
      int kc = ((c & 7) ^ (row & 7)) * 8;
      async_copy16(Ag + (size_t)row * 256 + k0 + kc, (void*)&sA[c * 8]);
    }
#pragma unroll
    for (int it = 0; it < 8; ++it) {
      int c = t + 256 * it;
      int row = c >> 3;
      int kc = ((c & 7) ^ (row & 7)) * 8;
      async_copy16(B + (size_t)row * 256 + k0 + kc, (void*)&sB[c * 8]);
    }
    __syncthreads();
#pragma unroll
    for (int ks = 0; ks < 2; ++ks) {
      bf16x8 af[4], bfr[8];
#pragma unroll
      for (int mi = 0; mi < 4; mi++)
        af[mi] = *(const bf16x8*)&sA[(wm + mi * 16 + fc) * 64 + (((ks * 4 + fr) ^ sw) * 8)];
#pragma unroll
      for (int ni = 0; ni < 8; ni++)
        bfr[ni] = *(const bf16x8*)&sB[(wn + ni * 16 + fc) * 64 + (((ks * 4 + fr) ^ sw) * 8)];
#pragma unroll
      for (int mi = 0; mi < 4; mi++)
#pragma unroll
        for (int ni = 0; ni < 8; ni++)
          acc[mi][ni] = __builtin_amdgcn_mfma_f32_16x16x32_bf16(af[mi], bfr[ni], acc[mi][ni], 0, 0, 0);
    }
  }

  // ---- epilogue: bias, row-norm, bf16 write, snorm ----
  float bv[8];
#pragma unroll
  for (int ni = 0; ni < 8; ni++) bv[ni] = bias[wn + ni * 16 + fc];

  __syncthreads();                       // sA dead; reuse as reduce buffer
  float* red = (float*)sA;               // [128][2]

#pragma unroll
  for (int mi = 0; mi < 4; mi++) {
    float ssq[4] = {0.f, 0.f, 0.f, 0.f};
#pragma unroll
    for (int ni = 0; ni < 8; ni++)
#pragma unroll
      for (int r = 0; r < 4; r++) {
        float v = acc[mi][ni][r] + bv[ni];
        acc[mi][ni][r] = v;
        ssq[r] += v * v;
      }
#pragma unroll
    for (int r = 0; r < 4; r++) {
      float v = ssq[r];
#pragma unroll
      for (int off = 1; off < 16; off <<= 1) v += __shfl_xor(v, off, 16);
      if (fc == 0) red[(wm + mi * 16 + fr * 4 + r) * 2 + (wn >> 7)] = v;
    }
  }
  __syncthreads();

  float* red2 = red + 256;
#pragma unroll
  for (int mi = 0; mi < 4; mi++) {
    float ssq2[4] = {0.f, 0.f, 0.f, 0.f};
#pragma unroll
    for (int r = 0; r < 4; r++) {
      int row = wm + mi * 16 + fr * 4 + r;
      float ss = red[row * 2] + red[row * 2 + 1];
      float rn = 1.f / fmaxf(sqrtf(ss), 1e-12f);
#pragma unroll
      for (int ni = 0; ni < 8; ni++) {
        u16 o = f2bf(acc[mi][ni][r] * rn);
        Mb[(size_t)(i0 + row) * 256 + wn + ni * 16 + fc] = o;
        float ov = bf2f(o);
        ssq2[r] += ov * ov;
      }
    }
#pragma unroll
    for (int r = 0; r < 4; r++) {
      float v = ssq2[r];
#pragma unroll
      for (int off = 1; off < 16; off <<= 1) v += __shfl_xor(v, off, 16);
      if (fc == 0) red2[(wm + mi * 16 + fr * 4 + r) * 2 + (wn >> 7)] = v;
    }
  }
  __syncthreads();
  if (t < 128) snorm[i0 + t] = red2[t * 2] + red2[t * 2 + 1];
}

// ---------------- symmetric Gram, A-resident + register-prefetched B ---------
// A strip (64KB) persists in LDS; B chunks (16KB) flow global->VGPR->LDS so
// barriers drain only lgkmcnt (ds_write), never a global load.
__global__ __launch_bounds__(256, 2)
void gram_sym(const u16* __restrict__ Mb, float* __restrict__ rsum) {
  __shared__ __bf16 sA[128 * 256];   // 64 KB, persistent per strip
  __shared__ __bf16 sB[128 * 64];    // 16 KB, per k0-chunk
  const int t = threadIdx.x;
  const int lane = t & 63, wave = t >> 6;
  const int wm = (wave >> 1) * 64, wn = (wave & 1) * 64;
  const int fr = lane >> 4, fc = lane & 15;
  const int sw = fc & 7;

  // ---- strip mapping (band closed form), long strips dispatched first ----
  int f = 2111 - blockIdx.x;
  int b = 0;
  while (f >= 2 * (b + 1) * (b + 2)) ++b;
  int rem = f - 2 * b * (b + 1);
  int r = rem / (b + 1);
  int q = rem - r * (b + 1);
  int k = 4 * b + 1 + r;
  const int i_t = 128 - k;
  const int jt0 = i_t + 4 * q;
  const int L = min(4, k - 4 * q);

  const int i0 = i_t * 128;
  const u16* Ag = Mb + (size_t)i0 * 256;

  // stage full A strip (once per strip; its vmcnt drain hits the first barrier only)
#pragma unroll
  for (int it = 0; it < 16; ++it) {
    int c = t + 256 * it;
    int row = c >> 5, pos = c & 31;
    int g = (pos & 24) | ((pos & 7) ^ (row & 7));
    async_copy16(Ag + (size_t)row * 256 + g * 8, (void*)&sA[c * 8]);
  }

  // per-thread B prefetch lane mapping
  const int pc0 = t, pr0 = t >> 3;                 // rows c>>3 for it=0..3
  int4 pb[4];
  {
    const u16* Bg = Mb + (size_t)jt0 * 128 * 256;
#pragma unroll
    for (int it = 0; it < 4; ++it) {
      int c = t + 256 * it;
      int row = c >> 3, gi = (c & 7) ^ (row & 7);
      pb[it] = *(const int4*)(Bg + (size_t)row * 256 + gi * 8);
    }
  }

  float rowacc[4][4];
#pragma unroll
  for (int a = 0; a < 4; a++)
#pragma unroll
    for (int rr = 0; rr < 4; rr++) rowacc[a][rr] = 0.f;

  f32x4 acc[4][4];
#pragma unroll
  for (int a = 0; a < 4; a++)
#pragma unroll
    for (int bb = 0; bb < 4; bb++) acc[a][bb] = (f32x4){0.f, 0.f, 0.f, 0.f};

  const int totalc = L * 4;
  for (int cc = 0; cc < totalc; ++cc) {
    const int kgb = (cc & 3) * 8;

    __syncthreads();                 // all waves done reading sB (prev chunk)
#pragma unroll
    for (int it = 0; it < 4; ++it)
      *(int4*)((char*)sB + (t + 256 * it) * 16) = pb[it];   // waits own pb vmcnt (landed)

    // prefetch next chunk (possibly next tile) while compute proceeds
    if (cc + 1 < totalc) {
      const u16* Bgn = Mb + (size_t)(jt0 + ((cc + 1) >> 2)) * 128 * 256;
      const int k0n = ((cc + 1) & 3) * 64;
#pragma unroll
      for (int it = 0; it < 4; ++it) {
        int c = t + 256 * it;
        int row = c >> 3, gi = (c & 7) ^ (row & 7);
        pb[it] = *(const int4*)(Bgn + (size_t)row * 256 + k0n + gi * 8);
      }
    }
    __syncthreads();                 // sB visible (lgkm only)

#pragma unroll
    for (int ks = 0; ks < 2; ++ks) {
      bf16x8 af[4], bfr[4];
#pragma unroll
      for (int mi = 0; mi < 4; mi++)
        af[mi] = *(const bf16x8*)&sA[(wm + mi * 16 + fc) * 256 + (kgb + ((ks * 4 + fr) ^ sw)) * 8];
#pragma unroll
      for (int ni = 0; ni < 4; ni++)
        bfr[ni] = *(const bf16x8*)&sB[(wn + ni * 16 + fc) * 64 + (((ks * 4 + fr) ^ sw) * 8)];
#pragma unroll
      for (int mi = 0; mi < 4; mi++)
#pragma unroll
        for (int ni = 0; ni < 4; ni++)
          acc[mi][ni] = __builtin_amdgcn_mfma_f32_16x16x32_bf16(af[mi], bfr[ni], acc[mi][ni], 0, 0, 0);
    }

    if ((cc & 3) == 3) {
      // tile epilogue
      const int j_t = jt0 + (cc >> 2);
      const int j0 = j_t * 128;
      float colp[4] = {0.f, 0.f, 0.f, 0.f};
#pragma unroll
      for (int mi = 0; mi < 4; mi++) {
#pragma unroll
        for (int ni = 0; ni < 4; ni++) {
          float e0 = __expf(acc[mi][ni][0] * INV_TAU);
          float e1 = __expf(acc[mi][ni][1] * INV_TAU);
          float e2 = __expf(acc[mi][ni][2] * INV_TAU);
          float e3 = __expf(acc[mi][ni][3] * INV_TAU);
          rowacc[mi][0] += e0; rowacc[mi][1] += e1;
          rowacc[mi][2] += e2; rowacc[mi][3] += e3;
          colp[ni] += e0 + e1 + e2 + e3;
          acc[mi][ni] = (f32x4){0.f, 0.f, 0.f, 0.f};
        }
      }
      if (j_t != i_t) {
#pragma unroll
        for (int ni = 0; ni < 4; ni++) {
          float v = colp[ni];
          v += __shfl_xor(v, 16, 64);
          v += __shfl_xor(v, 32, 64);
          if (fr == 0) atomicAdd(&rsum[j0 + wn + ni * 16 + fc], v);
        }
      }
    }
  }

  // strip-end: row-sum reduce across the 16 fc lanes, one atomic set
#pragma unroll
  for (int mi = 0; mi < 4; mi++) {
#pragma unroll
    for (int rr = 0; rr < 4; rr++) {
      float v = rowacc[mi][rr];
#pragma unroll
      for (int off = 1; off < 16; off <<= 1) v += __shfl_xor(v, off, 16);
      rowacc[mi][rr] = v;
    }
  }
  if (fc == 0) {
#pragma unroll
    for (int mi = 0; mi < 4; mi++) {
      int rbase = i0 + wm + mi * 16 + fr * 4;
      atomicAdd(&rsum[rbase + 0], rowacc[mi][0]);
      atomicAdd(&rsum[rbase + 1], rowacc[mi][1]);
      atomicAdd(&rsum[rbase + 2], rowacc[mi][2]);
      atomicAdd(&rsum[rbase + 3], rowacc[mi][3]);
    }
  }
  (void)pc0; (void)pr0;
}

// ---------------- final loss (4 rows / block) --------------------------------
__global__ void final_loss(const u16* __restrict__ Mb, const float* __restrict__ rsum,
                           const float* __restrict__ snorm, float* __restrict__ out) {
  int i = blockIdx.x * 4 + (threadIdx.x >> 6);
  int lane = threadIdx.x & 63;
  ushort4 ua = ((const ushort4*)(Mb + (size_t)i * 256))[lane];
  ushort4 ub = ((const ushort4*)(Mb + (size_t)(Nn + i) * 256))[lane];
  float d = bf2f(ua.x) * bf2f(ub.x) + bf2f(ua.y) * bf2f(ub.y) +
            bf2f(ua.z) * bf2f(ub.z) + bf2f(ua.w) * bf2f(ub.w);
#pragma unroll
  for (int off = 32; off; off >>= 1) d += __shfl_xor(d, off, 64);
  if (lane == 0) {
    float den1 = rsum[i] - __expf(snorm[i] * INV_TAU);
    float den2 = rsum[Nn + i] - __expf(snorm[Nn + i] * INV_TAU);
    out[i] = 0.5f * (logf(den1) + logf(den2)) - d * INV_TAU;
  }
}

extern "C" void kernel_launch(void* const* d_in, const int* in_sizes, int n_in,
                              void* d_out, int out_size, void* d_ws, size_t ws_size,
                              hipStream_t stream) {
  const float* z1 = (const float*)d_in[0];
  const float* z2 = (const float*)d_in[1];
  const float* W1 = (const float*)d_in[2];
  const float* b1 = (const float*)d_in[3];
  const float* W2 = (const float*)d_in[4];
  const float* b2 = (const float*)d_in[5];
  float* out = (float*)d_out;

  char* ws = (char*)d_ws;
  u16*   Zb    = (u16*)(ws);                          // 8 MB (reused as Mb)
  u16*   H1b   = (u16*)(ws + (8u << 20));             // 8 MB
  u16*   W1b   = (u16*)(ws + (16u << 20));            // 128 KB
  u16*   W2b   = (u16*)(ws + (16u << 20) + 131072);   // 128 KB
  float* rsum  = (float*)(ws + (16u << 20) + 262144); // 64 KB
  float* snorm = (float*)(ws + (16u << 20) + 262144 + 65536); // 64 KB
  u16*   Mb    = Zb;  // Zb dead after layer 1

  cast_all<<<1081344 / 256, 256, 0, stream>>>(z1, z2, W1, W2, Zb, W1b, W2b);

  // layer 1: elu(Z @ W1^T + b1) -> bf16
  mfma_gemm1<<<dim3(TWO_N / 128, 2), 256, 0, stream>>>(Zb, W1b, b1, H1b);

  // layer 2 + normalize + snorm + rsum zeroing
  gemm2_norm<<<TWO_N / 128, 256, 0, stream>>>(H1b, W2b, b2, Mb, snorm, rsum);

  // upper-triangle strips of <=4 tiles: 2112 blocks, long strips first
  gram_sym<<<2112, 256, 0, stream>>>(Mb, rsum);

  final_loss<<<Nn / 4, 256, 0, stream>>>(Mb, rsum, snorm, out);
}

// Round 7
// 188.369 us; speedup vs baseline: 1.5922x; 1.5922x over previous
//
#include <hip/hip_runtime.h>
#include <hip/hip_bf16.h>
#include <hip/hip_fp8.h>
#include <stdint.h>

#define Nn 8192
#define Dd 256
#define TWO_N 16384
#define INV_TAU 2.0f

typedef unsigned short u16;
typedef unsigned char u8;
typedef long long i64;
typedef __bf16 bf16x8 __attribute__((ext_vector_type(8)));
typedef float f32x4 __attribute__((ext_vector_type(4)));

typedef const __attribute__((address_space(1))) void* gas_ptr;
typedef __attribute__((address_space(3))) void* las_ptr;

__device__ __forceinline__ void async_copy16(const void* g, void* l) {
  __builtin_amdgcn_global_load_lds((gas_ptr)g, (las_ptr)l, 16, 0, 0);
}

__device__ __forceinline__ u16 f2bf(float x) {
  uint32_t u = __float_as_uint(x);
  u = u + 0x7fffu + ((u >> 16) & 1u);
  return (u16)(u >> 16);
}
__device__ __forceinline__ float bf2f(u16 u) {
  return __uint_as_float(((uint32_t)u) << 16);
}

// ---------------- fused cast fp32 -> bf16 ------------------------------------
__global__ void cast_all(const float* __restrict__ z1, const float* __restrict__ z2,
                         const float* __restrict__ W1, const float* __restrict__ W2,
                         u16* __restrict__ Zb, u16* __restrict__ W1b, u16* __restrict__ W2b) {
  int i = blockIdx.x * 256 + threadIdx.x;
  const float4* src; ushort4* dst; int off;
  if (i < 524288)       { src = (const float4*)z1; dst = (ushort4*)Zb;                      off = i; }
  else if (i < 1048576) { src = (const float4*)z2; dst = (ushort4*)(Zb + (size_t)Nn * Dd);  off = i - 524288; }
  else if (i < 1064960) { src = (const float4*)W1; dst = (ushort4*)W1b;                     off = i - 1048576; }
  else                  { src = (const float4*)W2; dst = (ushort4*)W2b;                     off = i - 1064960; }
  float4 v = src[off];
  ushort4 o;
  o.x = f2bf(v.x); o.y = f2bf(v.y); o.z = f2bf(v.z); o.w = f2bf(v.w);
  dst[off] = o;
}

// ---------------- layer-1 GEMM: elu(Z @ W1^T + b1) -> bf16 -------------------
__global__ __launch_bounds__(256)
void mfma_gemm1(const u16* __restrict__ A, const u16* __restrict__ B,
                const float* __restrict__ bias, u16* __restrict__ outp) {
  __shared__ __bf16 sA[128 * 64];
  __shared__ __bf16 sB[128 * 64];
  const int i0 = blockIdx.x * 128;
  const int j0 = blockIdx.y * 128;
  const int t = threadIdx.x;
  const int lane = t & 63, wave = t >> 6;
  const int wm = (wave >> 1) * 64, wn = (wave & 1) * 64;
  const int fr = lane >> 4, fc = lane & 15;
  const int sw = fc & 7;

  f32x4 acc[4][4];
#pragma unroll
  for (int a = 0; a < 4; a++)
#pragma unroll
    for (int b = 0; b < 4; b++) acc[a][b] = (f32x4){0.f, 0.f, 0.f, 0.f};

  const u16* Ag = A + (size_t)i0 * 256;
  const u16* Bg = B + (size_t)j0 * 256;

  for (int k0 = 0; k0 < 256; k0 += 64) {
    __syncthreads();
#pragma unroll
    for (int it = 0; it < 4; ++it) {
      int c = t + 256 * it;
      int row = c >> 3;
      int kc = ((c & 7) ^ (row & 7)) * 8;
      async_copy16(Ag + (size_t)row * 256 + k0 + kc, (void*)&sA[c * 8]);
      async_copy16(Bg + (size_t)row * 256 + k0 + kc, (void*)&sB[c * 8]);
    }
    __syncthreads();
#pragma unroll
    for (int ks = 0; ks < 2; ++ks) {
      bf16x8 af[4], bfr[4];
#pragma unroll
      for (int mi = 0; mi < 4; mi++)
        af[mi] = *(const bf16x8*)&sA[(wm + mi * 16 + fc) * 64 + (((ks * 4 + fr) ^ sw) * 8)];
#pragma unroll
      for (int ni = 0; ni < 4; ni++)
        bfr[ni] = *(const bf16x8*)&sB[(wn + ni * 16 + fc) * 64 + (((ks * 4 + fr) ^ sw) * 8)];
#pragma unroll
      for (int mi = 0; mi < 4; mi++)
#pragma unroll
        for (int ni = 0; ni < 4; ni++)
          acc[mi][ni] = __builtin_amdgcn_mfma_f32_16x16x32_bf16(af[mi], bfr[ni], acc[mi][ni], 0, 0, 0);
    }
  }

#pragma unroll
  for (int mi = 0; mi < 4; mi++) {
#pragma unroll
    for (int ni = 0; ni < 4; ni++) {
      int col = j0 + wn + ni * 16 + fc;
      float bv = bias[col];
#pragma unroll
      for (int r = 0; r < 4; r++) {
        int row = i0 + wm + mi * 16 + fr * 4 + r;
        float v = acc[mi][ni][r] + bv;
        v = v > 0.f ? v : (__expf(v) - 1.f);
        outp[(size_t)row * 256 + col] = f2bf(v);
      }
    }
  }
}

// ---------------- fused layer-2 GEMM + row-normalize + fp8 emit --------------
// 128 blocks; each computes 128 rows x 256 cols of H = H1 @ W2^T + b2,
// row-normalizes, writes bf16 Mb (for final_loss diagonal), fp8 Mf8 (for the
// Gram), and snorm = ||fp8(n)||^2 (exact diagonal cancellation). Zeroes rsum.
__global__ __launch_bounds__(256)
void gemm2_norm(const u16* __restrict__ A, const u16* __restrict__ B,
                const float* __restrict__ bias, u16* __restrict__ Mb,
                u8* __restrict__ Mf8, float* __restrict__ snorm,
                float* __restrict__ rsum) {
  __shared__ __bf16 sA[128 * 64];   // 16 KB
  __shared__ __bf16 sB[256 * 64];   // 32 KB
  const int i0 = blockIdx.x * 128;
  const int t = threadIdx.x;
  const int lane = t & 63, wave = t >> 6;
  const int wm = (wave >> 1) * 64, wn = (wave & 1) * 128;
  const int fr = lane >> 4, fc = lane & 15;
  const int sw = fc & 7;

  if (t < 128) rsum[i0 + t] = 0.f;

  f32x4 acc[4][8];
#pragma unroll
  for (int a = 0; a < 4; a++)
#pragma unroll
    for (int b = 0; b < 8; b++) acc[a][b] = (f32x4){0.f, 0.f, 0.f, 0.f};

  const u16* Ag = A + (size_t)i0 * 256;

  for (int k0 = 0; k0 < 256; k0 += 64) {
    __syncthreads();
#pragma unroll
    for (int it = 0; it < 4; ++it) {
      int c = t + 256 * it;
      int row = c >> 3;
      int kc = ((c & 7) ^ (row & 7)) * 8;
      async_copy16(Ag + (size_t)row * 256 + k0 + kc, (void*)&sA[c * 8]);
    }
#pragma unroll
    for (int it = 0; it < 8; ++it) {
      int c = t + 256 * it;
      int row = c >> 3;
      int kc = ((c & 7) ^ (row & 7)) * 8;
      async_copy16(B + (size_t)row * 256 + k0 + kc, (void*)&sB[c * 8]);
    }
    __syncthreads();
#pragma unroll
    for (int ks = 0; ks < 2; ++ks) {
      bf16x8 af[4], bfr[8];
#pragma unroll
      for (int mi = 0; mi < 4; mi++)
        af[mi] = *(const bf16x8*)&sA[(wm + mi * 16 + fc) * 64 + (((ks * 4 + fr) ^ sw) * 8)];
#pragma unroll
      for (int ni = 0; ni < 8; ni++)
        bfr[ni] = *(const bf16x8*)&sB[(wn + ni * 16 + fc) * 64 + (((ks * 4 + fr) ^ sw) * 8)];
#pragma unroll
      for (int mi = 0; mi < 4; mi++)
#pragma unroll
        for (int ni = 0; ni < 8; ni++)
          acc[mi][ni] = __builtin_amdgcn_mfma_f32_16x16x32_bf16(af[mi], bfr[ni], acc[mi][ni], 0, 0, 0);
    }
  }

  // ---- epilogue: bias, row-norm, bf16 + fp8 writes, fp8-based snorm ----
  float bv[8];
#pragma unroll
  for (int ni = 0; ni < 8; ni++) bv[ni] = bias[wn + ni * 16 + fc];

  __syncthreads();                       // sA dead; reuse as reduce buffer
  float* red = (float*)sA;               // [128][2]

#pragma unroll
  for (int mi = 0; mi < 4; mi++) {
    float ssq[4] = {0.f, 0.f, 0.f, 0.f};
#pragma unroll
    for (int ni = 0; ni < 8; ni++)
#pragma unroll
      for (int r = 0; r < 4; r++) {
        float v = acc[mi][ni][r] + bv[ni];
        acc[mi][ni][r] = v;
        ssq[r] += v * v;
      }
#pragma unroll
    for (int r = 0; r < 4; r++) {
      float v = ssq[r];
#pragma unroll
      for (int off = 1; off < 16; off <<= 1) v += __shfl_xor(v, off, 16);
      if (fc == 0) red[(wm + mi * 16 + fr * 4 + r) * 2 + (wn >> 7)] = v;
    }
  }
  __syncthreads();

  float* red2 = red + 256;
#pragma unroll
  for (int mi = 0; mi < 4; mi++) {
    float ssq2[4] = {0.f, 0.f, 0.f, 0.f};
#pragma unroll
    for (int r = 0; r < 4; r++) {
      int row = wm + mi * 16 + fr * 4 + r;
      float ss = red[row * 2] + red[row * 2 + 1];
      float rn = 1.f / fmaxf(sqrtf(ss), 1e-12f);
#pragma unroll
      for (int ni = 0; ni < 8; ni++) {
        float v = acc[mi][ni][r] * rn;
        Mb[(size_t)(i0 + row) * 256 + wn + ni * 16 + fc] = f2bf(v);
        __hip_fp8_e4m3 q(v);
        Mf8[(size_t)(i0 + row) * 256 + wn + ni * 16 + fc] = q.__x;
        float fv = (float)q;
        ssq2[r] += fv * fv;
      }
    }
#pragma unroll
    for (int r = 0; r < 4; r++) {
      float v = ssq2[r];
#pragma unroll
      for (int off = 1; off < 16; off <<= 1) v += __shfl_xor(v, off, 16);
      if (fc == 0) red2[(wm + mi * 16 + fr * 4 + r) * 2 + (wn >> 7)] = v;
    }
  }
  __syncthreads();
  if (t < 128) snorm[i0 + t] = red2[t * 2] + red2[t * 2 + 1];
}

// ---------------- symmetric Gram (fp8), A-resident + LDS-dbuf B --------------
// A strip (128x256 fp8 = 32KB) persists; B chunks (8KB) double-buffered. The
// prefetch of chunk cc+1 is issued AFTER the barrier, so the next barrier's
// forced vmcnt(0) drain targets loads a full compute-chunk old (landed).
// LDS 48KB -> 3 blocks/CU; launch_bounds(256,3) caps VGPR (no spill).
__global__ __launch_bounds__(256, 3)
void gram_sym(const u8* __restrict__ Mf8, float* __restrict__ rsum) {
  __shared__ u8 sA8[128 * 256];      // 32 KB, persistent per strip
  __shared__ u8 sB8[2][128 * 64];    // 2 x 8 KB double buffer
  const int t = threadIdx.x;
  const int lane = t & 63, wave = t >> 6;
  const int wm = (wave >> 1) * 64, wn = (wave & 1) * 64;
  const int fr = lane >> 4, fc = lane & 15;

  // ---- strip mapping (band closed form), long strips dispatched first ----
  int f = 2111 - blockIdx.x;
  int b = 0;
  while (f >= 2 * (b + 1) * (b + 2)) ++b;
  int rem = f - 2 * b * (b + 1);
  int r = rem / (b + 1);
  int q = rem - r * (b + 1);
  int k = 4 * b + 1 + r;
  const int i_t = 128 - k;
  const int jt0 = i_t + 4 * q;
  const int L = min(4, k - 4 * q);

  const int i0 = i_t * 128;
  const u8* Ag = Mf8 + (size_t)i0 * 256;

  // stage full A strip: 2048 x 16B copies; granule g of row r stored at
  // pos = (g&8)|((g&7)^(r&7))  -> conflict-free b64 fragment reads
#pragma unroll
  for (int it = 0; it < 8; ++it) {
    int c = t + 256 * it;
    int row = c >> 4, pos = c & 15;
    int g = (pos & 8) | ((pos & 7) ^ (row & 7));
    async_copy16(Ag + (size_t)row * 256 + g * 16, (void*)&sA8[c * 16]);
  }
  // stage B chunk 0 into sB8[0]
  {
    const u8* Bg = Mf8 + (size_t)jt0 * 128 * 256;
#pragma unroll
    for (int it = 0; it < 2; ++it) {
      int c = t + 256 * it;
      int row = c >> 2, pos = c & 3;
      int g = pos ^ ((row + (row >> 2)) & 3);
      async_copy16(Bg + (size_t)row * 256 + g * 16, (void*)&sB8[0][c * 16]);
    }
  }

  float rowacc[4][4];
#pragma unroll
  for (int a = 0; a < 4; a++)
#pragma unroll
    for (int rr = 0; rr < 4; rr++) rowacc[a][rr] = 0.f;

  f32x4 acc[4][4];
#pragma unroll
  for (int a = 0; a < 4; a++)
#pragma unroll
    for (int bb = 0; bb < 4; bb++) acc[a][bb] = (f32x4){0.f, 0.f, 0.f, 0.f};

  const int totalc = L * 4;
  for (int cc = 0; cc < totalc; ++cc) {
    __syncthreads();   // drains chunk cc staging (issued a full chunk ago; landed)

    // prefetch chunk cc+1 into the other buffer (drained only at NEXT barrier)
    if (cc + 1 < totalc) {
      const u8* Bgn = Mf8 + (size_t)(jt0 + ((cc + 1) >> 2)) * 128 * 256;
      const int k0n = ((cc + 1) & 3) * 64;
      u8* dst = sB8[(cc + 1) & 1];
#pragma unroll
      for (int it = 0; it < 2; ++it) {
        int c = t + 256 * it;
        int row = c >> 2, pos = c & 3;
        int g = pos ^ ((row + (row >> 2)) & 3);
        async_copy16(Bgn + (size_t)row * 256 + k0n + g * 16, (void*)&dst[c * 16]);
      }
    }

    // compute chunk cc from sA8 + sB8[cc&1]
    const int kch = cc & 3;
    const u8* sB = sB8[cc & 1];
#pragma unroll
    for (int ks = 0; ks < 2; ++ks) {
      i64 af[4], bf[4];
#pragma unroll
      for (int mi = 0; mi < 4; mi++) {
        int row = wm + mi * 16 + fc;
        int g16 = kch * 4 + ks * 2 + (fr >> 1);
        int sg = (g16 & 8) | ((g16 & 7) ^ (row & 7));
        af[mi] = *(const i64*)&sA8[row * 256 + sg * 16 + (fr & 1) * 8];
      }
#pragma unroll
      for (int ni = 0; ni < 4; ni++) {
        int row = wn + ni * 16 + fc;
        int g16 = ks * 2 + (fr >> 1);
        int sg = g16 ^ ((row + (row >> 2)) & 3);
        bf[ni] = *(const i64*)&sB[row * 64 + sg * 16 + (fr & 1) * 8];
      }
#pragma unroll
      for (int mi = 0; mi < 4; mi++)
#pragma unroll
        for (int ni = 0; ni < 4; ni++)
          acc[mi][ni] = __builtin_amdgcn_mfma_f32_16x16x32_fp8_fp8(af[mi], bf[ni], acc[mi][ni], 0, 0, 0);
    }

    if ((cc & 3) == 3) {
      // tile epilogue: e = exp(2*s); row partials persist; col-sums per tile
      const int j_t = jt0 + (cc >> 2);
      const int j0 = j_t * 128;
      float colp[4] = {0.f, 0.f, 0.f, 0.f};
#pragma unroll
      for (int mi = 0; mi < 4; mi++) {
#pragma unroll
        for (int ni = 0; ni < 4; ni++) {
          float e0 = __expf(acc[mi][ni][0] * INV_TAU);
          float e1 = __expf(acc[mi][ni][1] * INV_TAU);
          float e2 = __expf(acc[mi][ni][2] * INV_TAU);
          float e3 = __expf(acc[mi][ni][3] * INV_TAU);
          rowacc[mi][0] += e0; rowacc[mi][1] += e1;
          rowacc[mi][2] += e2; rowacc[mi][3] += e3;
          colp[ni] += e0 + e1 + e2 + e3;
          acc[mi][ni] = (f32x4){0.f, 0.f, 0.f, 0.f};
        }
      }
      if (j_t != i_t) {
#pragma unroll
        for (int ni = 0; ni < 4; ni++) {
          float v = colp[ni];
          v += __shfl_xor(v, 16, 64);
          v += __shfl_xor(v, 32, 64);
          if (fr == 0) atomicAdd(&rsum[j0 + wn + ni * 16 + fc], v);
        }
      }
    }
  }

  // strip-end: row-sum reduce across the 16 fc lanes, one atomic set
#pragma unroll
  for (int mi = 0; mi < 4; mi++) {
#pragma unroll
    for (int rr = 0; rr < 4; rr++) {
      float v = rowacc[mi][rr];
#pragma unroll
      for (int off = 1; off < 16; off <<= 1) v += __shfl_xor(v, off, 16);
      rowacc[mi][rr] = v;
    }
  }
  if (fc == 0) {
#pragma unroll
    for (int mi = 0; mi < 4; mi++) {
      int rbase = i0 + wm + mi * 16 + fr * 4;
      atomicAdd(&rsum[rbase + 0], rowacc[mi][0]);
      atomicAdd(&rsum[rbase + 1], rowacc[mi][1]);
      atomicAdd(&rsum[rbase + 2], rowacc[mi][2]);
      atomicAdd(&rsum[rbase + 3], rowacc[mi][3]);
    }
  }
}

// ---------------- final loss (4 rows / block) --------------------------------
__global__ void final_loss(const u16* __restrict__ Mb, const float* __restrict__ rsum,
                           const float* __restrict__ snorm, float* __restrict__ out) {
  int i = blockIdx.x * 4 + (threadIdx.x >> 6);
  int lane = threadIdx.x & 63;
  ushort4 ua = ((const ushort4*)(Mb + (size_t)i * 256))[lane];
  ushort4 ub = ((const ushort4*)(Mb + (size_t)(Nn + i) * 256))[lane];
  float d = bf2f(ua.x) * bf2f(ub.x) + bf2f(ua.y) * bf2f(ub.y) +
            bf2f(ua.z) * bf2f(ub.z) + bf2f(ua.w) * bf2f(ub.w);
#pragma unroll
  for (int off = 32; off; off >>= 1) d += __shfl_xor(d, off, 64);
  if (lane == 0) {
    float den1 = rsum[i] - __expf(snorm[i] * INV_TAU);
    float den2 = rsum[Nn + i] - __expf(snorm[Nn + i] * INV_TAU);
    out[i] = 0.5f * (logf(den1) + logf(den2)) - d * INV_TAU;
  }
}

extern "C" void kernel_launch(void* const* d_in, const int* in_sizes, int n_in,
                              void* d_out, int out_size, void* d_ws, size_t ws_size,
                              hipStream_t stream) {
  const float* z1 = (const float*)d_in[0];
  const float* z2 = (const float*)d_in[1];
  const float* W1 = (const float*)d_in[2];
  const float* b1 = (const float*)d_in[3];
  const float* W2 = (const float*)d_in[4];
  const float* b2 = (const float*)d_in[5];
  float* out = (float*)d_out;

  char* ws = (char*)d_ws;
  u16*   Zb    = (u16*)(ws);                          // 8 MB (reused as Mb)
  u16*   H1b   = (u16*)(ws + (8u << 20));             // 8 MB
  u8*    Mf8   = (u8*)(ws + (16u << 20));             // 4 MB
  u16*   W1b   = (u16*)(ws + (20u << 20));            // 128 KB
  u16*   W2b   = (u16*)(ws + (20u << 20) + 131072);   // 128 KB
  float* rsum  = (float*)(ws + (20u << 20) + 262144); // 64 KB
  float* snorm = (float*)(ws + (20u << 20) + 262144 + 65536); // 64 KB
  u16*   Mb    = Zb;  // Zb dead after layer 1

  cast_all<<<1081344 / 256, 256, 0, stream>>>(z1, z2, W1, W2, Zb, W1b, W2b);

  // layer 1: elu(Z @ W1^T + b1) -> bf16
  mfma_gemm1<<<dim3(TWO_N / 128, 2), 256, 0, stream>>>(Zb, W1b, b1, H1b);

  // layer 2 + normalize + bf16/fp8 emit + snorm + rsum zeroing
  gemm2_norm<<<TWO_N / 128, 256, 0, stream>>>(H1b, W2b, b2, Mb, Mf8, snorm, rsum);

  // upper-triangle strips of <=4 tiles: 2112 blocks, long strips first
  gram_sym<<<2112, 256, 0, stream>>>(Mf8, rsum);

  final_loss<<<Nn / 4, 256, 0, stream>>>(Mb, rsum, snorm, out);
}

// Round 8
// 181.872 us; speedup vs baseline: 1.6491x; 1.0357x over previous
//
#include <hip/hip_runtime.h>
#include <hip/hip_bf16.h>
#include <hip/hip_fp8.h>
#include <stdint.h>

#define Nn 8192
#define TWO_N 16384
#define INV_TAU 2.0f

typedef unsigned short u16;
typedef unsigned char u8;
typedef __bf16 bf16x8 __attribute__((ext_vector_type(8)));
typedef float f32x4 __attribute__((ext_vector_type(4)));
typedef int i32x8 __attribute__((ext_vector_type(8)));

typedef const __attribute__((address_space(1))) void* gas_ptr;
typedef __attribute__((address_space(3))) void* las_ptr;

__device__ __forceinline__ void async_copy16(const void* g, void* l) {
  __builtin_amdgcn_global_load_lds((gas_ptr)g, (las_ptr)l, 16, 0, 0);
}

__device__ __forceinline__ u16 f2bf(float x) {
  uint32_t u = __float_as_uint(x);
  u = u + 0x7fffu + ((u >> 16) & 1u);
  return (u16)(u >> 16);
}

// ---------------- layer-1 GEMM: elu(Z @ W1^T + b1) -> bf16 -------------------
// stages A from fp32 z1/z2 and B from fp32 W1 with inline bf16 convert
__global__ __launch_bounds__(256)
void mfma_gemm1(const float* __restrict__ z1, const float* __restrict__ z2,
                const float* __restrict__ W1, const float* __restrict__ bias,
                u16* __restrict__ outp) {
  __shared__ __bf16 sA[128 * 64];
  __shared__ __bf16 sB[128 * 64];
  const int bx = blockIdx.x;
  const int i0 = bx * 128;
  const int j0 = blockIdx.y * 128;
  const float* Zsrc = (bx < 64) ? (z1 + (size_t)i0 * 256) : (z2 + (size_t)(i0 - Nn) * 256);
  const float* Wsrc = W1 + (size_t)j0 * 256;
  const int t = threadIdx.x;
  const int lane = t & 63, wave = t >> 6;
  const int wm = (wave >> 1) * 64, wn = (wave & 1) * 64;
  const int fr = lane >> 4, fc = lane & 15;
  const int sw = fc & 7;

  f32x4 acc[4][4];
#pragma unroll
  for (int a = 0; a < 4; a++)
#pragma unroll
    for (int b = 0; b < 4; b++) acc[a][b] = (f32x4){0.f, 0.f, 0.f, 0.f};

  for (int k0 = 0; k0 < 256; k0 += 64) {
    __syncthreads();
#pragma unroll
    for (int it = 0; it < 4; ++it) {
      int c = t + 256 * it;
      int row = c >> 3;
      int g = (c & 7) ^ (row & 7);
      const float* sa = Zsrc + (size_t)row * 256 + k0 + g * 8;
      float4 a0 = *(const float4*)sa;
      float4 a1 = *(const float4*)(sa + 4);
      bf16x8 va = {(__bf16)a0.x, (__bf16)a0.y, (__bf16)a0.z, (__bf16)a0.w,
                   (__bf16)a1.x, (__bf16)a1.y, (__bf16)a1.z, (__bf16)a1.w};
      *(bf16x8*)&sA[c * 8] = va;
      const float* sb = Wsrc + (size_t)row * 256 + k0 + g * 8;
      float4 b0 = *(const float4*)sb;
      float4 b1v = *(const float4*)(sb + 4);
      bf16x8 vb = {(__bf16)b0.x, (__bf16)b0.y, (__bf16)b0.z, (__bf16)b0.w,
                   (__bf16)b1v.x, (__bf16)b1v.y, (__bf16)b1v.z, (__bf16)b1v.w};
      *(bf16x8*)&sB[c * 8] = vb;
    }
    __syncthreads();
#pragma unroll
    for (int ks = 0; ks < 2; ++ks) {
      bf16x8 af[4], bfr[4];
#pragma unroll
      for (int mi = 0; mi < 4; mi++)
        af[mi] = *(const bf16x8*)&sA[(wm + mi * 16 + fc) * 64 + (((ks * 4 + fr) ^ sw) * 8)];
#pragma unroll
      for (int ni = 0; ni < 4; ni++)
        bfr[ni] = *(const bf16x8*)&sB[(wn + ni * 16 + fc) * 64 + (((ks * 4 + fr) ^ sw) * 8)];
#pragma unroll
      for (int mi = 0; mi < 4; mi++)
#pragma unroll
        for (int ni = 0; ni < 4; ni++)
          acc[mi][ni] = __builtin_amdgcn_mfma_f32_16x16x32_bf16(af[mi], bfr[ni], acc[mi][ni], 0, 0, 0);
    }
  }

#pragma unroll
  for (int mi = 0; mi < 4; mi++) {
#pragma unroll
    for (int ni = 0; ni < 4; ni++) {
      int col = j0 + wn + ni * 16 + fc;
      float bv = bias[col];
#pragma unroll
      for (int r = 0; r < 4; r++) {
        int row = i0 + wm + mi * 16 + fr * 4 + r;
        float v = acc[mi][ni][r] + bv;
        v = v > 0.f ? v : (__expf(v) - 1.f);
        outp[(size_t)row * 256 + col] = f2bf(v);
      }
    }
  }
}

// ---------------- fused layer-2 GEMM + row-normalize + fp8 emit --------------
// 128 blocks; 128 rows x 256 cols of H = H1 @ W2^T + b2 (W2 cast inline),
// row-normalize, emit fp8 Mf8 + snorm = ||fp8(n)||^2. Zeroes rsum.
__global__ __launch_bounds__(256)
void gemm2_norm(const u16* __restrict__ A, const float* __restrict__ W2,
                const float* __restrict__ bias, u8* __restrict__ Mf8,
                float* __restrict__ snorm, float* __restrict__ rsum) {
  __shared__ __bf16 sA[128 * 64];   // 16 KB
  __shared__ __bf16 sB[256 * 64];   // 32 KB
  const int i0 = blockIdx.x * 128;
  const int t = threadIdx.x;
  const int lane = t & 63, wave = t >> 6;
  const int wm = (wave >> 1) * 64, wn = (wave & 1) * 128;
  const int fr = lane >> 4, fc = lane & 15;
  const int sw = fc & 7;

  if (t < 128) rsum[i0 + t] = 0.f;

  f32x4 acc[4][8];
#pragma unroll
  for (int a = 0; a < 4; a++)
#pragma unroll
    for (int b = 0; b < 8; b++) acc[a][b] = (f32x4){0.f, 0.f, 0.f, 0.f};

  const u16* Ag = A + (size_t)i0 * 256;

  for (int k0 = 0; k0 < 256; k0 += 64) {
    __syncthreads();
#pragma unroll
    for (int it = 0; it < 4; ++it) {
      int c = t + 256 * it;
      int row = c >> 3;
      int kc = ((c & 7) ^ (row & 7)) * 8;
      async_copy16(Ag + (size_t)row * 256 + k0 + kc, (void*)&sA[c * 8]);
    }
#pragma unroll
    for (int it = 0; it < 8; ++it) {
      int c = t + 256 * it;
      int row = c >> 3;
      int g = (c & 7) ^ (row & 7);
      const float* sb = W2 + (size_t)row * 256 + k0 + g * 8;
      float4 b0 = *(const float4*)sb;
      float4 b1v = *(const float4*)(sb + 4);
      bf16x8 vb = {(__bf16)b0.x, (__bf16)b0.y, (__bf16)b0.z, (__bf16)b0.w,
                   (__bf16)b1v.x, (__bf16)b1v.y, (__bf16)b1v.z, (__bf16)b1v.w};
      *(bf16x8*)&sB[c * 8] = vb;
    }
    __syncthreads();
#pragma unroll
    for (int ks = 0; ks < 2; ++ks) {
      bf16x8 af[4], bfr[8];
#pragma unroll
      for (int mi = 0; mi < 4; mi++)
        af[mi] = *(const bf16x8*)&sA[(wm + mi * 16 + fc) * 64 + (((ks * 4 + fr) ^ sw) * 8)];
#pragma unroll
      for (int ni = 0; ni < 8; ni++)
        bfr[ni] = *(const bf16x8*)&sB[(wn + ni * 16 + fc) * 64 + (((ks * 4 + fr) ^ sw) * 8)];
#pragma unroll
      for (int mi = 0; mi < 4; mi++)
#pragma unroll
        for (int ni = 0; ni < 8; ni++)
          acc[mi][ni] = __builtin_amdgcn_mfma_f32_16x16x32_bf16(af[mi], bfr[ni], acc[mi][ni], 0, 0, 0);
    }
  }

  // ---- epilogue: bias, row-norm, fp8 write, fp8-based snorm ----
  float bv[8];
#pragma unroll
  for (int ni = 0; ni < 8; ni++) bv[ni] = bias[wn + ni * 16 + fc];

  __syncthreads();                       // sA dead; reuse as reduce buffer
  float* red = (float*)sA;               // [128][2]

#pragma unroll
  for (int mi = 0; mi < 4; mi++) {
    float ssq[4] = {0.f, 0.f, 0.f, 0.f};
#pragma unroll
    for (int ni = 0; ni < 8; ni++)
#pragma unroll
      for (int r = 0; r < 4; r++) {
        float v = acc[mi][ni][r] + bv[ni];
        acc[mi][ni][r] = v;
        ssq[r] += v * v;
      }
#pragma unroll
    for (int r = 0; r < 4; r++) {
      float v = ssq[r];
#pragma unroll
      for (int off = 1; off < 16; off <<= 1) v += __shfl_xor(v, off, 16);
      if (fc == 0) red[(wm + mi * 16 + fr * 4 + r) * 2 + (wn >> 7)] = v;
    }
  }
  __syncthreads();

  float* red2 = red + 256;
#pragma unroll
  for (int mi = 0; mi < 4; mi++) {
    float ssq2[4] = {0.f, 0.f, 0.f, 0.f};
#pragma unroll
    for (int r = 0; r < 4; r++) {
      int row = wm + mi * 16 + fr * 4 + r;
      float ss = red[row * 2] + red[row * 2 + 1];
      float rn = 1.f / fmaxf(sqrtf(ss), 1e-12f);
#pragma unroll
      for (int ni = 0; ni < 8; ni++) {
        float v = acc[mi][ni][r] * rn;
        __hip_fp8_e4m3 q(v);
        Mf8[(size_t)(i0 + row) * 256 + wn + ni * 16 + fc] = q.__x;
        float fv = (float)q;
        ssq2[r] += fv * fv;
      }
    }
#pragma unroll
    for (int r = 0; r < 4; r++) {
      float v = ssq2[r];
#pragma unroll
      for (int off = 1; off < 16; off <<= 1) v += __shfl_xor(v, off, 16);
      if (fc == 0) red2[(wm + mi * 16 + fr * 4 + r) * 2 + (wn >> 7)] = v;
    }
  }
  __syncthreads();
  if (t < 128) snorm[i0 + t] = red2[t * 2] + red2[t * 2 + 1];
}

// ---------------- symmetric Gram, MX fp8 K=128, A-in-regs, B dbuf ------------
// A fragments (4 mi x 2 Kblock x 32B) gathered from global into VGPRs once per
// strip. B tiles (32KB full-K) double-buffered in LDS with a 16-slot xor
// swizzle (slot = g ^ (row&15)) -> stride-1-like b128 bank distribution.
// One barrier per tile; prefetch issued behind the barrier.
__global__ __launch_bounds__(256, 2)
void gram_sym(const u8* __restrict__ Mf8, float* __restrict__ rsum) {
  __shared__ u8 sB8[2][128 * 256];   // 2 x 32 KB
  const int t = threadIdx.x;
  const int lane = t & 63, wave = t >> 6;
  const int wm = (wave >> 1) * 64, wn = (wave & 1) * 64;
  const int fr = lane >> 4, fc = lane & 15;

  // ---- strip mapping (band closed form), long strips dispatched first ----
  int f = 2111 - blockIdx.x;
  int b = 0;
  while (f >= 2 * (b + 1) * (b + 2)) ++b;
  int rem = f - 2 * b * (b + 1);
  int r = rem / (b + 1);
  int q = rem - r * (b + 1);
  int k = 4 * b + 1 + r;
  const int i_t = 128 - k;
  const int jt0 = i_t + 4 * q;
  const int L = min(4, k - 4 * q);
  const int i0 = i_t * 128;

  // stage B(tile 0) into buffer 0
  {
    const u8* Bg = Mf8 + (size_t)jt0 * 128 * 256;
#pragma unroll
    for (int it = 0; it < 8; ++it) {
      int c = t + 256 * it;
      int row = c >> 4, slot = c & 15;
      int g = slot ^ (row & 15);
      async_copy16(Bg + (size_t)row * 256 + g * 16, (void*)&sB8[0][c * 16]);
    }
  }

  // gather A fragments into registers (L3-resident; once per strip)
  i32x8 afr[4][2];
  {
    const u8* Ag = Mf8 + (size_t)i0 * 256;
#pragma unroll
    for (int mi = 0; mi < 4; ++mi) {
      const u8* rp = Ag + (size_t)(wm + mi * 16 + fc) * 256 + fr * 32;
#pragma unroll
      for (int kb = 0; kb < 2; ++kb) {
        int4 lo = *(const int4*)(rp + kb * 128);
        int4 hi = *(const int4*)(rp + kb * 128 + 16);
        afr[mi][kb] = (i32x8){lo.x, lo.y, lo.z, lo.w, hi.x, hi.y, hi.z, hi.w};
      }
    }
  }

  float rowacc[4][4];
#pragma unroll
  for (int a = 0; a < 4; a++)
#pragma unroll
    for (int rr = 0; rr < 4; rr++) rowacc[a][rr] = 0.f;

  for (int jt = 0; jt < L; ++jt) {
    const int j_t = jt0 + jt;
    const int j0 = j_t * 128;
    const u8* sB = &sB8[jt & 1][0];

    __syncthreads();   // drains B(jt) staging (issued >=1 tile ago) + frees other buf

    // prefetch B(jt+1) behind the barrier (drained only at NEXT barrier)
    if (jt + 1 < L) {
      const u8* Bg = Mf8 + (size_t)(j_t + 1) * 128 * 256;
      u8* dst = &sB8[(jt + 1) & 1][0];
#pragma unroll
      for (int it = 0; it < 8; ++it) {
        int c = t + 256 * it;
        int row = c >> 4, slot = c & 15;
        int g = slot ^ (row & 15);
        async_copy16(Bg + (size_t)row * 256 + g * 16, (void*)&dst[c * 16]);
      }
    }

    f32x4 acc[4][4];
#pragma unroll
    for (int a = 0; a < 4; a++)
#pragma unroll
      for (int bb = 0; bb < 4; bb++) acc[a][bb] = (f32x4){0.f, 0.f, 0.f, 0.f};

#pragma unroll
    for (int kb = 0; kb < 2; ++kb) {
      i32x8 bfrag[4];
#pragma unroll
      for (int ni = 0; ni < 4; ++ni) {
        const u8* base = sB + (wn + ni * 16 + fc) * 256;
        int g0 = kb * 8 + fr * 2;
        int4 lo = *(const int4*)(base + ((g0 ^ fc) * 16));
        int4 hi = *(const int4*)(base + (((g0 + 1) ^ fc) * 16));
        bfrag[ni] = (i32x8){lo.x, lo.y, lo.z, lo.w, hi.x, hi.y, hi.z, hi.w};
      }
#pragma unroll
      for (int mi = 0; mi < 4; mi++)
#pragma unroll
        for (int ni = 0; ni < 4; ni++)
          acc[mi][ni] = __builtin_amdgcn_mfma_scale_f32_16x16x128_f8f6f4(
              afr[mi][kb], bfrag[ni], acc[mi][ni], 0, 0, 0, 0x7F, 0, 0x7F);
    }

    // tile epilogue: e = exp(2*s); row partials persist; col-sums per tile
    float colp[4] = {0.f, 0.f, 0.f, 0.f};
#pragma unroll
    for (int mi = 0; mi < 4; mi++) {
#pragma unroll
      for (int ni = 0; ni < 4; ni++) {
        float e0 = __expf(acc[mi][ni][0] * INV_TAU);
        float e1 = __expf(acc[mi][ni][1] * INV_TAU);
        float e2 = __expf(acc[mi][ni][2] * INV_TAU);
        float e3 = __expf(acc[mi][ni][3] * INV_TAU);
        rowacc[mi][0] += e0; rowacc[mi][1] += e1;
        rowacc[mi][2] += e2; rowacc[mi][3] += e3;
        colp[ni] += e0 + e1 + e2 + e3;
      }
    }
    if (j_t != i_t) {
#pragma unroll
      for (int ni = 0; ni < 4; ni++) {
        float v = colp[ni];
        v += __shfl_xor(v, 16, 64);
        v += __shfl_xor(v, 32, 64);
        if (fr == 0) atomicAdd(&rsum[j0 + wn + ni * 16 + fc], v);
      }
    }
  }

  // strip-end: row-sum reduce across the 16 fc lanes, one atomic set
#pragma unroll
  for (int mi = 0; mi < 4; mi++) {
#pragma unroll
    for (int rr = 0; rr < 4; rr++) {
      float v = rowacc[mi][rr];
#pragma unroll
      for (int off = 1; off < 16; off <<= 1) v += __shfl_xor(v, off, 16);
      rowacc[mi][rr] = v;
    }
  }
  if (fc == 0) {
#pragma unroll
    for (int mi = 0; mi < 4; mi++) {
      int rbase = i0 + wm + mi * 16 + fr * 4;
      atomicAdd(&rsum[rbase + 0], rowacc[mi][0]);
      atomicAdd(&rsum[rbase + 1], rowacc[mi][1]);
      atomicAdd(&rsum[rbase + 2], rowacc[mi][2]);
      atomicAdd(&rsum[rbase + 3], rowacc[mi][3]);
    }
  }
}

// ---------------- final loss (4 rows / block), fp8 diagonal ------------------
__global__ void final_loss(const u8* __restrict__ Mf8, const float* __restrict__ rsum,
                           const float* __restrict__ snorm, float* __restrict__ out) {
  int i = blockIdx.x * 4 + (threadIdx.x >> 6);
  int lane = threadIdx.x & 63;
  unsigned int ua = ((const unsigned int*)(Mf8 + (size_t)i * 256))[lane];
  unsigned int ub = ((const unsigned int*)(Mf8 + (size_t)(Nn + i) * 256))[lane];
  float d = 0.f;
#pragma unroll
  for (int e = 0; e < 4; ++e) {
    __hip_fp8_e4m3 qa, qb;
    qa.__x = (ua >> (8 * e)) & 0xFF;
    qb.__x = (ub >> (8 * e)) & 0xFF;
    d += (float)qa * (float)qb;
  }
#pragma unroll
  for (int off = 32; off; off >>= 1) d += __shfl_xor(d, off, 64);
  if (lane == 0) {
    float den1 = rsum[i] - __expf(snorm[i] * INV_TAU);
    float den2 = rsum[Nn + i] - __expf(snorm[Nn + i] * INV_TAU);
    out[i] = 0.5f * (logf(den1) + logf(den2)) - d * INV_TAU;
  }
}

extern "C" void kernel_launch(void* const* d_in, const int* in_sizes, int n_in,
                              void* d_out, int out_size, void* d_ws, size_t ws_size,
                              hipStream_t stream) {
  const float* z1 = (const float*)d_in[0];
  const float* z2 = (const float*)d_in[1];
  const float* W1 = (const float*)d_in[2];
  const float* b1 = (const float*)d_in[3];
  const float* W2 = (const float*)d_in[4];
  const float* b2 = (const float*)d_in[5];
  float* out = (float*)d_out;

  char* ws = (char*)d_ws;
  u16*   H1b   = (u16*)(ws);                          // 8 MB
  u8*    Mf8   = (u8*)(ws + (8u << 20));              // 4 MB
  float* rsum  = (float*)(ws + (12u << 20));          // 64 KB
  float* snorm = (float*)(ws + (12u << 20) + 65536);  // 64 KB

  // layer 1 (inline fp32->bf16 cast of z and W1)
  mfma_gemm1<<<dim3(TWO_N / 128, 2), 256, 0, stream>>>(z1, z2, W1, b1, H1b);

  // layer 2 + normalize + fp8 emit + snorm + rsum zeroing (inline W2 cast)
  gemm2_norm<<<TWO_N / 128, 256, 0, stream>>>(H1b, W2, b2, Mf8, snorm, rsum);

  // upper-triangle strips of <=4 tiles: 2112 blocks, long strips first
  gram_sym<<<2112, 256, 0, stream>>>(Mf8, rsum);

  final_loss<<<Nn / 4, 256, 0, stream>>>(Mf8, rsum, snorm, out);
}

// Round 9
// 176.377 us; speedup vs baseline: 1.7004x; 1.0312x over previous
//
#include <hip/hip_runtime.h>
#include <hip/hip_bf16.h>
#include <hip/hip_fp8.h>
#include <stdint.h>

#define Nn 8192
#define TWO_N 16384
#define INV_TAU 2.0f

typedef unsigned short u16;
typedef unsigned char u8;
typedef __bf16 bf16x8 __attribute__((ext_vector_type(8)));
typedef float f32x4 __attribute__((ext_vector_type(4)));
typedef int i32x8 __attribute__((ext_vector_type(8)));

typedef const __attribute__((address_space(1))) void* gas_ptr;
typedef __attribute__((address_space(3))) void* las_ptr;

__device__ __forceinline__ void async_copy16(const void* g, void* l) {
  __builtin_amdgcn_global_load_lds((gas_ptr)g, (las_ptr)l, 16, 0, 0);
}

// ---------------- fused MLP + normalize + fp8 emit ---------------------------
// 256 blocks x 64 rows. Layer1: elu(Z @ W1^T + b1) -> bf16 H1 in LDS (never
// hits HBM). Layer2: H1 @ W2^T + b2 from LDS. Then cross-wave row-norm,
// fp8 Mf8 emit, snorm = ||fp8(n)||^2, rsum zeroing.
// Wave w computes all 64 rows x cols [w*64, w*64+64) in both layers.
__global__ __launch_bounds__(256)
void mlp_norm(const float* __restrict__ z1, const float* __restrict__ z2,
              const float* __restrict__ W1, const float* __restrict__ b1,
              const float* __restrict__ W2, const float* __restrict__ b2,
              u8* __restrict__ Mf8, float* __restrict__ snorm,
              float* __restrict__ rsum) {
  __shared__ __bf16 sZ[64 * 64];    // 8 KB  (layer1 A; reduce scratch later)
  __shared__ __bf16 sW[256 * 64];   // 32 KB (W chunk, both layers)
  __shared__ __bf16 sH[64 * 256];   // 32 KB (H1, full K for layer 2)
  const int bx = blockIdx.x;
  const int i0 = bx * 64;
  const float* Zsrc = (bx < 128) ? (z1 + (size_t)i0 * 256)
                                 : (z2 + (size_t)(i0 - Nn) * 256);
  const int t = threadIdx.x;
  const int lane = t & 63, wave = t >> 6;
  const int wn = wave * 64;
  const int fr = lane >> 4, fc = lane & 15;
  const int sw = fc & 7;

  if (t < 64) rsum[i0 + t] = 0.f;

  f32x4 acc[4][4];
#pragma unroll
  for (int a = 0; a < 4; a++)
#pragma unroll
    for (int b = 0; b < 4; b++) acc[a][b] = (f32x4){0.f, 0.f, 0.f, 0.f};

  // ---- layer 1 ----
  for (int k0 = 0; k0 < 256; k0 += 64) {
    __syncthreads();
#pragma unroll
    for (int it = 0; it < 2; ++it) {               // Z: 512 granules
      int c = t + 256 * it;
      int row = c >> 3, g = (c & 7) ^ (row & 7);
      const float* s = Zsrc + (size_t)row * 256 + k0 + g * 8;
      float4 a0 = *(const float4*)s, a1 = *(const float4*)(s + 4);
      bf16x8 v = {(__bf16)a0.x, (__bf16)a0.y, (__bf16)a0.z, (__bf16)a0.w,
                  (__bf16)a1.x, (__bf16)a1.y, (__bf16)a1.z, (__bf16)a1.w};
      *(bf16x8*)&sZ[c * 8] = v;
    }
#pragma unroll
    for (int it = 0; it < 8; ++it) {               // W1: 2048 granules
      int c = t + 256 * it;
      int row = c >> 3, g = (c & 7) ^ (row & 7);
      const float* s = W1 + (size_t)row * 256 + k0 + g * 8;
      float4 a0 = *(const float4*)s, a1 = *(const float4*)(s + 4);
      bf16x8 v = {(__bf16)a0.x, (__bf16)a0.y, (__bf16)a0.z, (__bf16)a0.w,
                  (__bf16)a1.x, (__bf16)a1.y, (__bf16)a1.z, (__bf16)a1.w};
      *(bf16x8*)&sW[c * 8] = v;
    }
    __syncthreads();
#pragma unroll
    for (int ks = 0; ks < 2; ++ks) {
      bf16x8 af[4], bfr[4];
#pragma unroll
      for (int mi = 0; mi < 4; mi++)
        af[mi] = *(const bf16x8*)&sZ[(mi * 16 + fc) * 64 + (((ks * 4 + fr) ^ sw) * 8)];
#pragma unroll
      for (int ni = 0; ni < 4; ni++)
        bfr[ni] = *(const bf16x8*)&sW[(wn + ni * 16 + fc) * 64 + (((ks * 4 + fr) ^ sw) * 8)];
#pragma unroll
      for (int mi = 0; mi < 4; mi++)
#pragma unroll
        for (int ni = 0; ni < 4; ni++)
          acc[mi][ni] = __builtin_amdgcn_mfma_f32_16x16x32_bf16(af[mi], bfr[ni], acc[mi][ni], 0, 0, 0);
    }
  }

  // layer-1 epilogue: bias + elu -> bf16 into sH (granule-xor swizzled rows)
  {
    float bv[4];
#pragma unroll
    for (int ni = 0; ni < 4; ni++) bv[ni] = b1[wn + ni * 16 + fc];
#pragma unroll
    for (int mi = 0; mi < 4; mi++)
#pragma unroll
      for (int ni = 0; ni < 4; ni++) {
        int col = wn + ni * 16 + fc;
        int gc = col >> 3;
#pragma unroll
        for (int r = 0; r < 4; r++) {
          int row = mi * 16 + fr * 4 + r;
          float v = acc[mi][ni][r] + bv[ni];
          v = v > 0.f ? v : (__expf(v) - 1.f);
          int pos = (gc & 24) | ((gc & 7) ^ (row & 7));
          sH[row * 256 + pos * 8 + (col & 7)] = (__bf16)v;
          acc[mi][ni][r] = 0.f;
        }
      }
  }

  // ---- layer 2 (A = sH, resident full-K) ----
  for (int k0 = 0; k0 < 256; k0 += 64) {
    __syncthreads();   // also guarantees: all sH writes done before first read
#pragma unroll
    for (int it = 0; it < 8; ++it) {               // W2: 2048 granules
      int c = t + 256 * it;
      int row = c >> 3, g = (c & 7) ^ (row & 7);
      const float* s = W2 + (size_t)row * 256 + k0 + g * 8;
      float4 a0 = *(const float4*)s, a1 = *(const float4*)(s + 4);
      bf16x8 v = {(__bf16)a0.x, (__bf16)a0.y, (__bf16)a0.z, (__bf16)a0.w,
                  (__bf16)a1.x, (__bf16)a1.y, (__bf16)a1.z, (__bf16)a1.w};
      *(bf16x8*)&sW[c * 8] = v;
    }
    __syncthreads();
    const int kgb = k0 >> 3;
#pragma unroll
    for (int ks = 0; ks < 2; ++ks) {
      bf16x8 af[4], bfr[4];
#pragma unroll
      for (int mi = 0; mi < 4; mi++)
        af[mi] = *(const bf16x8*)&sH[(mi * 16 + fc) * 256 + (kgb + (((ks * 4 + fr) ^ sw))) * 8];
#pragma unroll
      for (int ni = 0; ni < 4; ni++)
        bfr[ni] = *(const bf16x8*)&sW[(wn + ni * 16 + fc) * 64 + (((ks * 4 + fr) ^ sw) * 8)];
#pragma unroll
      for (int mi = 0; mi < 4; mi++)
#pragma unroll
        for (int ni = 0; ni < 4; ni++)
          acc[mi][ni] = __builtin_amdgcn_mfma_f32_16x16x32_bf16(af[mi], bfr[ni], acc[mi][ni], 0, 0, 0);
    }
  }

  // ---- epilogue: bias, cross-wave row-norm, fp8 emit, snorm ----
  float bv[4];
#pragma unroll
  for (int ni = 0; ni < 4; ni++) bv[ni] = b2[wn + ni * 16 + fc];

  __syncthreads();                 // sZ dead; reuse as reduce scratch
  float* red = (float*)sZ;         // [64 rows][4 waves]
  float* red2 = red + 256;

#pragma unroll
  for (int mi = 0; mi < 4; mi++) {
    float ssq[4] = {0.f, 0.f, 0.f, 0.f};
#pragma unroll
    for (int ni = 0; ni < 4; ni++)
#pragma unroll
      for (int r = 0; r < 4; r++) {
        float v = acc[mi][ni][r] + bv[ni];
        acc[mi][ni][r] = v;
        ssq[r] += v * v;
      }
#pragma unroll
    for (int r = 0; r < 4; r++) {
      float v = ssq[r];
#pragma unroll
      for (int off = 1; off < 16; off <<= 1) v += __shfl_xor(v, off, 16);
      if (fc == 0) red[(mi * 16 + fr * 4 + r) * 4 + wave] = v;
    }
  }
  __syncthreads();

#pragma unroll
  for (int mi = 0; mi < 4; mi++) {
    float ssq2[4] = {0.f, 0.f, 0.f, 0.f};
#pragma unroll
    for (int r = 0; r < 4; r++) {
      int row = mi * 16 + fr * 4 + r;
      float ss = red[row * 4] + red[row * 4 + 1] + red[row * 4 + 2] + red[row * 4 + 3];
      float rn = 1.f / fmaxf(sqrtf(ss), 1e-12f);
#pragma unroll
      for (int ni = 0; ni < 4; ni++) {
        float v = acc[mi][ni][r] * rn;
        __hip_fp8_e4m3 q(v);
        Mf8[(size_t)(i0 + row) * 256 + wn + ni * 16 + fc] = q.__x;
        float fv = (float)q;
        ssq2[r] += fv * fv;
      }
    }
#pragma unroll
    for (int r = 0; r < 4; r++) {
      float v = ssq2[r];
#pragma unroll
      for (int off = 1; off < 16; off <<= 1) v += __shfl_xor(v, off, 16);
      if (fc == 0) red2[(mi * 16 + fr * 4 + r) * 4 + wave] = v;
    }
  }
  __syncthreads();
  if (t < 64)
    snorm[i0 + t] = red2[t * 4] + red2[t * 4 + 1] + red2[t * 4 + 2] + red2[t * 4 + 3];
}

// ---------------- symmetric Gram, MX fp8 K=128, A-in-regs, B dbuf ------------
__global__ __launch_bounds__(256, 2)
void gram_sym(const u8* __restrict__ Mf8, float* __restrict__ rsum) {
  __shared__ u8 sB8[2][128 * 256];   // 2 x 32 KB
  const int t = threadIdx.x;
  const int lane = t & 63, wave = t >> 6;
  const int wm = (wave >> 1) * 64, wn = (wave & 1) * 64;
  const int fr = lane >> 4, fc = lane & 15;

  // ---- strip mapping (band closed form), long strips dispatched first ----
  int f = 2111 - blockIdx.x;
  int b = 0;
  while (f >= 2 * (b + 1) * (b + 2)) ++b;
  int rem = f - 2 * b * (b + 1);
  int r = rem / (b + 1);
  int q = rem - r * (b + 1);
  int k = 4 * b + 1 + r;
  const int i_t = 128 - k;
  const int jt0 = i_t + 4 * q;
  const int L = min(4, k - 4 * q);
  const int i0 = i_t * 128;

  // stage B(tile 0) into buffer 0
  {
    const u8* Bg = Mf8 + (size_t)jt0 * 128 * 256;
#pragma unroll
    for (int it = 0; it < 8; ++it) {
      int c = t + 256 * it;
      int row = c >> 4, slot = c & 15;
      int g = slot ^ (row & 15);
      async_copy16(Bg + (size_t)row * 256 + g * 16, (void*)&sB8[0][c * 16]);
    }
  }

  // gather A fragments into registers (L2/L3-resident; once per strip)
  i32x8 afr[4][2];
  {
    const u8* Ag = Mf8 + (size_t)i0 * 256;
#pragma unroll
    for (int mi = 0; mi < 4; ++mi) {
      const u8* rp = Ag + (size_t)(wm + mi * 16 + fc) * 256 + fr * 32;
#pragma unroll
      for (int kb = 0; kb < 2; ++kb) {
        int4 lo = *(const int4*)(rp + kb * 128);
        int4 hi = *(const int4*)(rp + kb * 128 + 16);
        afr[mi][kb] = (i32x8){lo.x, lo.y, lo.z, lo.w, hi.x, hi.y, hi.z, hi.w};
      }
    }
  }

  float rowacc[4][4];
#pragma unroll
  for (int a = 0; a < 4; a++)
#pragma unroll
    for (int rr = 0; rr < 4; rr++) rowacc[a][rr] = 0.f;

  for (int jt = 0; jt < L; ++jt) {
    const int j_t = jt0 + jt;
    const int j0 = j_t * 128;
    const u8* sB = &sB8[jt & 1][0];

    __syncthreads();   // drains B(jt) staging (issued >=1 tile ago; landed)

    if (jt + 1 < L) {  // prefetch B(jt+1) behind the barrier
      const u8* Bg = Mf8 + (size_t)(j_t + 1) * 128 * 256;
      u8* dst = &sB8[(jt + 1) & 1][0];
#pragma unroll
      for (int it = 0; it < 8; ++it) {
        int c = t + 256 * it;
        int row = c >> 4, slot = c & 15;
        int g = slot ^ (row & 15);
        async_copy16(Bg + (size_t)row * 256 + g * 16, (void*)&dst[c * 16]);
      }
    }

    f32x4 acc[4][4];
#pragma unroll
    for (int a = 0; a < 4; a++)
#pragma unroll
      for (int bb = 0; bb < 4; bb++) acc[a][bb] = (f32x4){0.f, 0.f, 0.f, 0.f};

#pragma unroll
    for (int kb = 0; kb < 2; ++kb) {
      i32x8 bfrag[4];
#pragma unroll
      for (int ni = 0; ni < 4; ++ni) {
        const u8* base = sB + (wn + ni * 16 + fc) * 256;
        int g0 = kb * 8 + fr * 2;
        int4 lo = *(const int4*)(base + ((g0 ^ fc) * 16));
        int4 hi = *(const int4*)(base + (((g0 + 1) ^ fc) * 16));
        bfrag[ni] = (i32x8){lo.x, lo.y, lo.z, lo.w, hi.x, hi.y, hi.z, hi.w};
      }
#pragma unroll
      for (int mi = 0; mi < 4; mi++)
#pragma unroll
        for (int ni = 0; ni < 4; ni++)
          acc[mi][ni] = __builtin_amdgcn_mfma_scale_f32_16x16x128_f8f6f4(
              afr[mi][kb], bfrag[ni], acc[mi][ni], 0, 0, 0, 0x7F, 0, 0x7F);
    }

    // tile epilogue
    float colp[4] = {0.f, 0.f, 0.f, 0.f};
#pragma unroll
    for (int mi = 0; mi < 4; mi++) {
#pragma unroll
      for (int ni = 0; ni < 4; ni++) {
        float e0 = __expf(acc[mi][ni][0] * INV_TAU);
        float e1 = __expf(acc[mi][ni][1] * INV_TAU);
        float e2 = __expf(acc[mi][ni][2] * INV_TAU);
        float e3 = __expf(acc[mi][ni][3] * INV_TAU);
        rowacc[mi][0] += e0; rowacc[mi][1] += e1;
        rowacc[mi][2] += e2; rowacc[mi][3] += e3;
        colp[ni] += e0 + e1 + e2 + e3;
      }
    }
    if (j_t != i_t) {
#pragma unroll
      for (int ni = 0; ni < 4; ni++) {
        float v = colp[ni];
        v += __shfl_xor(v, 16, 64);
        v += __shfl_xor(v, 32, 64);
        if (fr == 0) atomicAdd(&rsum[j0 + wn + ni * 16 + fc], v);
      }
    }
  }

  // strip-end: row-sum reduce across the 16 fc lanes, one atomic set
#pragma unroll
  for (int mi = 0; mi < 4; mi++) {
#pragma unroll
    for (int rr = 0; rr < 4; rr++) {
      float v = rowacc[mi][rr];
#pragma unroll
      for (int off = 1; off < 16; off <<= 1) v += __shfl_xor(v, off, 16);
      rowacc[mi][rr] = v;
    }
  }
  if (fc == 0) {
#pragma unroll
    for (int mi = 0; mi < 4; mi++) {
      int rbase = i0 + wm + mi * 16 + fr * 4;
      atomicAdd(&rsum[rbase + 0], rowacc[mi][0]);
      atomicAdd(&rsum[rbase + 1], rowacc[mi][1]);
      atomicAdd(&rsum[rbase + 2], rowacc[mi][2]);
      atomicAdd(&rsum[rbase + 3], rowacc[mi][3]);
    }
  }
}

// ---------------- final loss (4 rows / block), fp8 diagonal ------------------
__global__ void final_loss(const u8* __restrict__ Mf8, const float* __restrict__ rsum,
                           const float* __restrict__ snorm, float* __restrict__ out) {
  int i = blockIdx.x * 4 + (threadIdx.x >> 6);
  int lane = threadIdx.x & 63;
  unsigned int ua = ((const unsigned int*)(Mf8 + (size_t)i * 256))[lane];
  unsigned int ub = ((const unsigned int*)(Mf8 + (size_t)(Nn + i) * 256))[lane];
  float d = 0.f;
#pragma unroll
  for (int e = 0; e < 4; ++e) {
    __hip_fp8_e4m3 qa, qb;
    qa.__x = (ua >> (8 * e)) & 0xFF;
    qb.__x = (ub >> (8 * e)) & 0xFF;
    d += (float)qa * (float)qb;
  }
#pragma unroll
  for (int off = 32; off; off >>= 1) d += __shfl_xor(d, off, 64);
  if (lane == 0) {
    float den1 = rsum[i] - __expf(snorm[i] * INV_TAU);
    float den2 = rsum[Nn + i] - __expf(snorm[Nn + i] * INV_TAU);
    out[i] = 0.5f * (logf(den1) + logf(den2)) - d * INV_TAU;
  }
}

extern "C" void kernel_launch(void* const* d_in, const int* in_sizes, int n_in,
                              void* d_out, int out_size, void* d_ws, size_t ws_size,
                              hipStream_t stream) {
  const float* z1 = (const float*)d_in[0];
  const float* z2 = (const float*)d_in[1];
  const float* W1 = (const float*)d_in[2];
  const float* b1 = (const float*)d_in[3];
  const float* W2 = (const float*)d_in[4];
  const float* b2 = (const float*)d_in[5];
  float* out = (float*)d_out;

  char* ws = (char*)d_ws;
  u8*    Mf8   = (u8*)(ws);                          // 4 MB
  float* rsum  = (float*)(ws + (4u << 20));          // 64 KB
  float* snorm = (float*)(ws + (4u << 20) + 65536);  // 64 KB

  // fused MLP (both layers) + normalize + fp8 emit + snorm + rsum zeroing
  mlp_norm<<<256, 256, 0, stream>>>(z1, z2, W1, b1, W2, b2, Mf8, snorm, rsum);

  // upper-triangle strips of <=4 tiles: 2112 blocks, long strips first
  gram_sym<<<2112, 256, 0, stream>>>(Mf8, rsum);

  final_loss<<<Nn / 4, 256, 0, stream>>>(Mf8, rsum, snorm, out);
}